// Round 7
// baseline (679.582 us; speedup 1.0000x reference)
//
#include <hip/hip_runtime.h>

// 3-layer LSTM, B=4096, T=336, F=12, H=50, fp32 in/out.
// ROUND-12: WAVE-PER-LAYER + PROJECTION HELPERS (barrier paradigm only; the
// softbarrier line R9-R11 is abandoned after 2 container deaths).
// Invariant to beat: homogeneous waves + per-tick barrier phase-lock the CU
// into serial LDS->MFMA->VALU phases (~2450cy/tick across 4 variants).
// Fix: HETEROGENEOUS wave roles so phases interleave across SIMDs even in
// lockstep. One wave owns a WHOLE layer (13 tiles share one B-operand; the
// self-recurrence never crosses waves); two helper waves compute the
// inter-layer input projections (MFMA-only, no transcendentals).
//   w0: P1  z1 = b1 + Wih1 * h0-plane   (26 MFMA, 13 z-writes)  SIMD0
//   w1: L0  h0 = cell(b0 + [Wih0|Whh0]*[x|h0])                  SIMD1
//   w2: L1  h1 = cell(z1 + Whh1*h1)                             SIMD2
//   w3: L2  h2 = cell(z2 + Whh2*h2)                             SIMD3
//   w4: P2  z2 = b2 + Wih2 * h1-plane                           SIMD0
// Cell waves: VALU-heavy (13 cells), 505cy MFMA. Proj waves: MFMA-only;
// paired on SIMD0 (1010cy matrix, ~300 VALU). Complementary per-SIMD load.
// Chain L0->P1->L1->P2->L2 with one-tick hops; reads from [p], writes to
// [1-p] -> ONE __syncthreads per tick is sufficient (no spin-waits).
// Layer delay 0/2/4 -> 340 ticks. Weights VGPR-resident (104/wave).
// 320 threads = 5 waves; grid 256 (1 block/CU).

#define Bsz 4096
#define Tt  336
#define BT  16
#define NTH 320

typedef _Float16 half8 __attribute__((ext_vector_type(8)));
typedef float    floatx4 __attribute__((ext_vector_type(4)));

// Planes: 64-half rows, 8 chunks (16B), XOR-chunk swizzle (&7).
// act0 row: [x 0..11 | h0 12..61 | pad]  act1/2 row: [h 0..49 | pad]
// z bufs: [parity][tile m][n][q] floatx4 (f32 gate quad per lane).
struct __align__(16) SMem {
  _Float16 act0[2][BT * 64];
  _Float16 act1[2][BT * 64];
  _Float16 act2[2][BT * 64];
  float z1[2][13 * 256];
  float z2[2][13 * 256];
};  // 12288 + 53248 = 65536 B

__device__ __forceinline__ int offA(int n, int L) {
  return n * 64 + ((((L >> 3) ^ n) & 7) << 3) + (L & 7);
}

// z gate-prescaled: gates i,f,o hold -log2(e)*z ; gate g holds 2*log2(e)*z.
// Fused: sig(i)*tanh(g) = (eg-1)/((1+ei)(1+eg));
//        sig(o)*tanh(c) = (ec-1)/((1+eo)(1+ec)), ec = e^{2c}.
__device__ __forceinline__ float lstm_cell(floatx4 z, float& c) {
  float ei = __builtin_amdgcn_exp2f(z[0]);
  float ef = __builtin_amdgcn_exp2f(z[1]);
  float eg = __builtin_amdgcn_exp2f(z[2]);
  float eo = __builtin_amdgcn_exp2f(z[3]);
  float fg  = __builtin_amdgcn_rcpf(1.f + ef);                    // sigmoid(f)
  float itg = (eg - 1.f) *
              __builtin_amdgcn_rcpf((1.f + ei) * (1.f + eg));     // sig(i)*tanh(g)
  c = fg * c + itg;
  float ec = __builtin_amdgcn_exp2f(2.885390082f * c);            // e^{2c}
  return (ec - 1.f) *
         __builtin_amdgcn_rcpf((1.f + eo) * (1.f + ec));          // sig(o)*tanh(c)
}

// A-fragment (8 halfs), gate-permuted + gate-prescaled.
// k in [0,lena) -> Wa ; k in [offb,offb+lenb) -> Wb ; else 0.
__device__ __forceinline__ half8 wfrag2(const float* __restrict__ Wa, int lena,
                                        const float* __restrict__ Wb, int offb,
                                        int lenb, int R, int k0) {
  half8 r = {};
  int u = R >> 2, g = R & 3;
  float sc = (g == 2) ? 2.885390082f : -1.442695041f;
  if (u < 50) {
    int row = g * 50 + u;
#pragma unroll
    for (int j = 0; j < 8; ++j) {
      int k = k0 + j;
      float v = 0.f;
      if (Wa && k < lena)                          v = Wa[row * lena + k];
      else if (Wb && k >= offb && k < offb + lenb) v = Wb[row * lenb + (k - offb)];
      r[j] = (_Float16)(sc * v);
    }
  }
  return r;
}

#define MFMA(a, b, acc) __builtin_amdgcn_mfma_f32_16x16x32_f16((a), (b), (acc), 0, 0, 0)

__global__ __launch_bounds__(NTH, 1)
void lstm_mfma_kernel(const float* __restrict__ x,
                      const float* __restrict__ Wih0, const float* __restrict__ Whh0,
                      const float* __restrict__ bih0, const float* __restrict__ bhh0,
                      const float* __restrict__ Wih1, const float* __restrict__ Whh1,
                      const float* __restrict__ bih1, const float* __restrict__ bhh1,
                      const float* __restrict__ Wih2, const float* __restrict__ Whh2,
                      const float* __restrict__ bih2, const float* __restrict__ bhh2,
                      const float* __restrict__ Wlin, const float* __restrict__ blin,
                      float* __restrict__ out) {
  __shared__ SMem sm;
  const int tid  = threadIdx.x;
  const int blk  = blockIdx.x;
  const int lane = tid & 63;
  const int w    = tid >> 6;       // wave 0..4 -> SIMD w&3 (w4 pairs w0)
  const int n    = lane & 15;      // batch col / A-row in tile
  const int q    = lane >> 4;      // quad
  const int zi   = n * 4 + q;      // floatx4 index within a z tile

  // ---- zero LDS (h(-1)=0 for all layers/parities, pads=0) ----
  {
    int* zp = (int*)&sm;
    for (int i = tid; i < (int)(sizeof(SMem) / 4); i += NTH) zp[i] = 0;
  }

  // ---- role-dependent weight sources ----
  const float *WA, *WB, *bi, *bh;
  int lena, offb, lenb;
  switch (w) {
    case 0:  WA = nullptr; lena = 0;  WB = Wih1;    offb = 12; lenb = 50;
             bi = bih1; bh = bhh1; break;                       // P1
    case 1:  WA = Wih0;    lena = 12; WB = Whh0;    offb = 12; lenb = 50;
             bi = bih0; bh = bhh0; break;                       // L0
    case 2:  WA = Whh1;    lena = 50; WB = nullptr; offb = 0;  lenb = 0;
             bi = nullptr; bh = nullptr; break;                 // L1
    case 3:  WA = Whh2;    lena = 50; WB = nullptr; offb = 0;  lenb = 0;
             bi = nullptr; bh = nullptr; break;                 // L2
    default: WA = Wih2;    lena = 50; WB = nullptr; offb = 0;  lenb = 0;
             bi = bih2; bh = bhh2; break;                       // P2
  }

  // ---- role-dependent plane / z-buffer pointers ----
  _Float16 (*pl)[BT * 64];   // cell waves: own plane (r/w). proj: source plane (r).
  float (*zs)[13 * 256];     // proj: dest. L1/L2: source. L0: unused.
  switch (w) {
    case 0:  pl = sm.act0; zs = sm.z1; break;
    case 1:  pl = sm.act0; zs = sm.z1; break;   // zs unused
    case 2:  pl = sm.act1; zs = sm.z1; break;
    case 3:  pl = sm.act2; zs = sm.z2; break;
    default: pl = sm.act1; zs = sm.z2; break;
  }

  // ---- per-tile weight fragments, bias seeds, write offsets, c-state ----
  half8   af[13][2];
  floatx4 bia[13];
  float   cst[13];
  int     wo[13];
  bool    uok[13];
#pragma unroll
  for (int m = 0; m < 13; ++m) {
    int R = 16 * m + n;
    int u = 4 * m + q;
    int uc = (u < 50) ? u : 49;
    uok[m] = (u < 50);
    cst[m] = 0.f;
    bia[m] = (floatx4){0, 0, 0, 0};
    wo[m] = (w == 1) ? offA(n, 12 + uc) : offA(n, uc);
    af[m][0] = wfrag2(WA, lena, WB, offb, lenb, R, q * 8);
    af[m][1] = wfrag2(WA, lena, WB, offb, lenb, R, 32 + q * 8);
    if (bi && u < 50) {
#pragma unroll
      for (int g = 0; g < 4; ++g) {
        float sc = (g == 2) ? 2.885390082f : -1.442695041f;
        bia[m][g] = sc * (bi[g * 50 + u] + bh[g * 50 + u]);
      }
    }
  }

  // ---- lane-constant LDS read offsets (halfs) ----
  const int ro0 = offA(n, q * 8), ro1 = offA(n, 32 + q * 8);

  // ---- x stager (wave 1): 16 rows x 12 feats = 192 = 64 lanes x 3 ----
  const int xidx = lane * 3;
  const int r0 = xidx / 12,       f0 = xidx - r0 * 12;
  const int r1 = (xidx + 1) / 12, f1 = (xidx + 1) - r1 * 12;
  const int r2 = (xidx + 2) / 12, f2 = (xidx + 2) - r2 * 12;
  const int sx0 = offA(r0, f0), sx1 = offA(r1, f1), sx2 = offA(r2, f2);
  const float* xp0 = x + ((size_t)(blk * BT + r0) * Tt) * 12 + f0;
  const float* xp1 = x + ((size_t)(blk * BT + r1) * Tt) * 12 + f1;
  const float* xp2 = x + ((size_t)(blk * BT + r2) * Tt) * 12 + f2;
  float xn0 = 0.f, xn1 = 0.f, xn2 = 0.f;

  __syncthreads();   // zero-fill visible
  if (w == 1) {
    sm.act0[0][sx0] = (_Float16)xp0[0];   // x(0) into parity-0 plane
    sm.act0[0][sx1] = (_Float16)xp1[0];
    sm.act0[0][sx2] = (_Float16)xp2[0];
    xn0 = xp0[12]; xn1 = xp1[12]; xn2 = xp2[12];   // x(1)
  }
  __syncthreads();

  // Tick TAU (parity p = TAU&1): read planes/bufs [p], write [1-p]; one
  // barrier per tick. Windows: L0 step TAU (TAU<=335); P1 z1 for step TAU-1
  // (1..336); L1 step TAU-2 (2..337); P2 z2 for step TAU-3 (3..338);
  // L2 step TAU-4 (4..339). CHK=1 -> literal-TAU folds (fill/drain).
#define TICK(p, TAU, CHK)                                                  \
  {                                                                        \
    if (w == 1) {                                                          \
      if (!(CHK) || (TAU) <= 335) {                                        \
        half8 b0 = *(const half8*)&pl[p][ro0];                             \
        half8 b1 = *(const half8*)&pl[p][ro1];                             \
        _Float16* sw = &pl[1 - (p)][0];                                    \
        _Pragma("unroll")                                                  \
        for (int m = 0; m < 13; ++m) {                                     \
          floatx4 z = bia[m];                                              \
          z = MFMA(af[m][0], b0, z);                                       \
          z = MFMA(af[m][1], b1, z);                                       \
          float h = lstm_cell(z, cst[m]);                                  \
          if (uok[m]) sw[wo[m]] = (_Float16)h;                             \
        }                                                                  \
        if ((TAU) + 1 < Tt) {                                              \
          sw[sx0] = (_Float16)xn0; sw[sx1] = (_Float16)xn1;                \
          sw[sx2] = (_Float16)xn2;                                         \
        }                                                                  \
        if ((TAU) + 2 < Tt) {                                              \
          xn0 = xp0[((TAU) + 2) * 12]; xn1 = xp1[((TAU) + 2) * 12];        \
          xn2 = xp2[((TAU) + 2) * 12];                                     \
        }                                                                  \
      }                                                                    \
    } else if (w == 0 || w == 4) {                                         \
      if (!(CHK) || ((w == 0) ? ((TAU) >= 1 && (TAU) <= 336)               \
                              : ((TAU) >= 3 && (TAU) <= 338))) {           \
        half8 b0 = *(const half8*)&pl[p][ro0];                             \
        half8 b1 = *(const half8*)&pl[p][ro1];                             \
        floatx4* zw = (floatx4*)&zs[1 - (p)][0];                           \
        _Pragma("unroll")                                                  \
        for (int m = 0; m < 13; ++m) {                                     \
          floatx4 z = bia[m];                                              \
          z = MFMA(af[m][0], b0, z);                                       \
          z = MFMA(af[m][1], b1, z);                                       \
          zw[m * 64 + zi] = z;                                             \
        }                                                                  \
      }                                                                    \
    } else {                                                               \
      if (!(CHK) || ((w == 2) ? ((TAU) >= 2 && (TAU) <= 337)               \
                              : ((TAU) >= 4 && (TAU) <= 339))) {           \
        half8 b0 = *(const half8*)&pl[p][ro0];                             \
        half8 b1 = *(const half8*)&pl[p][ro1];                             \
        const floatx4* zr = (const floatx4*)&zs[p][0];                     \
        _Float16* sw = &pl[1 - (p)][0];                                    \
        _Pragma("unroll")                                                  \
        for (int m = 0; m < 13; ++m) {                                     \
          floatx4 z = zr[m * 64 + zi];                                     \
          z = MFMA(af[m][0], b0, z);                                       \
          z = MFMA(af[m][1], b1, z);                                       \
          float h = lstm_cell(z, cst[m]);                                  \
          if (uok[m]) sw[wo[m]] = (_Float16)h;                             \
        }                                                                  \
      }                                                                    \
    }                                                                      \
    __syncthreads();                                                       \
  }

  // fill (literal TAU -> activity folds at compile time)
  TICK(0, 0, 1)
  TICK(1, 1, 1)
  TICK(0, 2, 1)
  TICK(1, 3, 1)
  // steady: ticks 4..335 (332 ticks, unroll-2 for literal parity; all roles
  // active in this range so CHK=0 removes window tests)
#pragma unroll 1
  for (int t = 4; t < Tt; t += 2) {
    TICK(0, t, 0)
    TICK(1, t + 1, 0)
  }
  // drain
  TICK(0, 336, 1)
  TICK(1, 337, 1)
  TICK(0, 338, 1)
  TICK(1, 339, 1)
#undef TICK

  // ---- epilogue: out[r] = b_lin + h2(335) . W_lin ----
  // L2 step 335 ran at tick 339 (p=1) -> wrote act2[0] (halfs 0..49)
  if (tid < BT) {
    float s = blin[0];
    for (int uu = 0; uu < 50; ++uu)
      s += Wlin[uu] * (float)sm.act2[0][offA(tid, uu)];
    out[blk * BT + tid] = s;
  }
}

extern "C" void kernel_launch(void* const* d_in, const int* in_sizes, int n_in,
                              void* d_out, int out_size, void* d_ws, size_t ws_size,
                              hipStream_t stream) {
  const float* x    = (const float*)d_in[0];
  const float* Wih0 = (const float*)d_in[1];
  const float* Whh0 = (const float*)d_in[2];
  const float* bih0 = (const float*)d_in[3];
  const float* bhh0 = (const float*)d_in[4];
  const float* Wih1 = (const float*)d_in[5];
  const float* Whh1 = (const float*)d_in[6];
  const float* bih1 = (const float*)d_in[7];
  const float* bhh1 = (const float*)d_in[8];
  const float* Wih2 = (const float*)d_in[9];
  const float* Whh2 = (const float*)d_in[10];
  const float* bih2 = (const float*)d_in[11];
  const float* bhh2 = (const float*)d_in[12];
  const float* Wlin = (const float*)d_in[13];
  const float* blin = (const float*)d_in[14];
  float* outp = (float*)d_out;

  dim3 grid(Bsz / BT);   // 256 blocks, 1 per CU
  dim3 block(NTH);       // 5 waves: proj pair on SIMD0, cell waves solo
  lstm_mfma_kernel<<<grid, block, 0, stream>>>(
      x, Wih0, Whh0, bih0, bhh0, Wih1, Whh1, bih1, bhh1,
      Wih2, Whh2, bih2, bhh2, Wlin, blin, outp);
}

// Round 8
// 399.075 us; speedup vs baseline: 1.7029x; 1.7029x over previous
//
#include <hip/hip_runtime.h>

// 3-layer LSTM, B=4096, T=336, F=12, H=50, fp32 in/out.
// ROUND-13: BALANCED HETEROGENEOUS WAVES (fix of R12's two implementation
// failures, which masked the actual hypothesis):
//  - R12 spilled (whole layer per wave ~200 VGPR -> 17.6MB/dispatch scratch
//    writes). Now 16 waves with SMALL tile counts: 12 cell waves (3-4 tiles,
//    ~90 VGPR) + 4 proj waves (6-7 tiles, ~120 VGPR), launch_bounds(1024,4).
//  - R12's z buffer used zi=n*4+q (lane permutation -> 8-way bank conflict,
//    6.9e7). Now LANE-LINEAR: z[(tile)*64+lane] floatx4 — proj lane l's
//    accumulator quad is exactly cell lane l's C-operand (same MFMA layout),
//    and consecutive lanes hit consecutive 16B -> conflict-free.
// Dataflow (same as R12, which PASSED): chain L0 -> P1 -> L1 -> P2 -> L2,
// one-tick hops, one __syncthreads per tick, read [p] / write [1-p].
//   P1: z1 = b1 + Wih1*h0   P2: z2 = b2 + Wih2*h1   (MFMA-only waves)
//   L0: h0 = cell(b0 + [Wih0|Whh0]*[x|h0])
//   L1: h1 = cell(z1 + Whh1*h1)   L2: h2 = cell(z2 + Whh2*h2)
// Windows: L0 tau<=335, P1 1..336, L1 2..337, P2 3..338, L2 4..339 (340 ticks).
// SIMD balance (simd = w&3): each SIMD = 1 proj + 3 cell waves, cells
// {10,10,10,9}. Proj waves' MFMA/LDS phase interleaves with cell waves'
// transcendental chains — the role-split overlap homogeneous designs lack.
// 1024 threads = 16 waves, grid 256 (1 block/CU).

#define Bsz 4096
#define Tt  336
#define BT  16
#define NTH 1024

typedef _Float16 half8 __attribute__((ext_vector_type(8)));
typedef float    floatx4 __attribute__((ext_vector_type(4)));

// act planes: 64-half rows, 8 chunks (16B), XOR-chunk swizzle (&7).
// act0 row: [x 0..11 | h0 12..61 | pad]  act1/2 row: [h 0..49 | pad]
// z bufs: [parity][tile*64 + lane] floatx4, lane-linear (conflict-free).
struct __align__(16) SMem {
  _Float16 act0[2][BT * 64];
  _Float16 act1[2][BT * 64];
  _Float16 act2[2][BT * 64];
  floatx4 z1[2][13 * 64];
  floatx4 z2[2][13 * 64];
};  // 12288 + 53248 = 65536 B

__device__ __forceinline__ int offA(int n, int L) {
  return n * 64 + ((((L >> 3) ^ n) & 7) << 3) + (L & 7);
}

// z gate-prescaled: gates i,f,o hold -log2(e)*z ; gate g holds 2*log2(e)*z.
// Fused: sig(i)*tanh(g) = (eg-1)/((1+ei)(1+eg));
//        sig(o)*tanh(c) = (ec-1)/((1+eo)(1+ec)), ec = e^{2c}.
__device__ __forceinline__ float lstm_cell(floatx4 z, float& c) {
  float ei = __builtin_amdgcn_exp2f(z[0]);
  float ef = __builtin_amdgcn_exp2f(z[1]);
  float eg = __builtin_amdgcn_exp2f(z[2]);
  float eo = __builtin_amdgcn_exp2f(z[3]);
  float fg  = __builtin_amdgcn_rcpf(1.f + ef);
  float itg = (eg - 1.f) *
              __builtin_amdgcn_rcpf((1.f + ei) * (1.f + eg));
  c = fg * c + itg;
  float ec = __builtin_amdgcn_exp2f(2.885390082f * c);
  return (ec - 1.f) *
         __builtin_amdgcn_rcpf((1.f + eo) * (1.f + ec));
}

// A-fragment (8 halfs), gate-permuted + gate-prescaled.
// k in [0,lena) -> Wa ; k in [offb,offb+lenb) -> Wb ; else 0.
__device__ __forceinline__ half8 wfrag2(const float* __restrict__ Wa, int lena,
                                        const float* __restrict__ Wb, int offb,
                                        int lenb, int R, int k0) {
  half8 r = {};
  int u = R >> 2, g = R & 3;
  float sc = (g == 2) ? 2.885390082f : -1.442695041f;
  if (u < 50) {
    int row = g * 50 + u;
#pragma unroll
    for (int j = 0; j < 8; ++j) {
      int k = k0 + j;
      float v = 0.f;
      if (Wa && k < lena)                          v = Wa[row * lena + k];
      else if (Wb && k >= offb && k < offb + lenb) v = Wb[row * lenb + (k - offb)];
      r[j] = (_Float16)(sc * v);
    }
  }
  return r;
}

#define MFMA(a, b, acc) __builtin_amdgcn_mfma_f32_16x16x32_f16((a), (b), (acc), 0, 0, 0)

__global__ __launch_bounds__(NTH, 4)
void lstm_mfma_kernel(const float* __restrict__ x,
                      const float* __restrict__ Wih0, const float* __restrict__ Whh0,
                      const float* __restrict__ bih0, const float* __restrict__ bhh0,
                      const float* __restrict__ Wih1, const float* __restrict__ Whh1,
                      const float* __restrict__ bih1, const float* __restrict__ bhh1,
                      const float* __restrict__ Wih2, const float* __restrict__ Whh2,
                      const float* __restrict__ bih2, const float* __restrict__ bhh2,
                      const float* __restrict__ Wlin, const float* __restrict__ blin,
                      float* __restrict__ out) {
  __shared__ SMem sm;
  const int tid  = threadIdx.x;
  const int blk  = blockIdx.x;
  const int lane = tid & 63;
  const int w    = tid >> 6;       // wave 0..15; SIMD = w&3
  const int n    = lane & 15;
  const int q    = lane >> 4;

  // ---- zero LDS ----
  {
    int* zp = (int*)&sm;
    for (int i = tid; i < (int)(sizeof(SMem) / 4); i += NTH) zp[i] = 0;
  }

  // ---- wave -> (role, tile base, tile count) ----
  // roles: 0=P1, 1=P2, 2=L0, 3=L1, 4=L2. SIMD k = {proj, L0, L1, L2}:
  //   SIMD0: w0 P1a(7) | w4 L0(4) | w8  L1(3) | w12 L2(3)   = 10 cells
  //   SIMD1: w1 P1b(6) | w5 L0(3) | w9  L1(4) | w13 L2(3)   = 10
  //   SIMD2: w2 P2a(7) | w6 L0(3) | w10 L1(3) | w14 L2(4)   = 10
  //   SIMD3: w3 P2b(6)+x | w7 L0(3) | w11 L1(3) | w15 L2(3) = 9
  int role, tb, nt;
  switch (w) {
    case 0:  role = 0; tb = 0;  nt = 7; break;
    case 1:  role = 0; tb = 7;  nt = 6; break;
    case 2:  role = 1; tb = 0;  nt = 7; break;
    case 3:  role = 1; tb = 7;  nt = 6; break;
    case 4:  role = 2; tb = 0;  nt = 4; break;
    case 5:  role = 2; tb = 4;  nt = 3; break;
    case 6:  role = 2; tb = 7;  nt = 3; break;
    case 7:  role = 2; tb = 10; nt = 3; break;
    case 8:  role = 3; tb = 0;  nt = 3; break;
    case 9:  role = 3; tb = 3;  nt = 4; break;
    case 10: role = 3; tb = 7;  nt = 3; break;
    case 11: role = 3; tb = 10; nt = 3; break;
    case 12: role = 4; tb = 0;  nt = 3; break;
    case 13: role = 4; tb = 3;  nt = 3; break;
    case 14: role = 4; tb = 6;  nt = 4; break;
    default: role = 4; tb = 10; nt = 3; break;
  }

  // ---- lane-constant act-plane read offsets ----
  const int ro0 = offA(n, q * 8), ro1 = offA(n, 32 + q * 8);

  // ---- x stager (w3): 192 = 64 lanes x 3 ----
  const int xidx = lane * 3;
  const int xr0 = xidx / 12,       xf0 = xidx - xr0 * 12;
  const int xr1 = (xidx + 1) / 12, xf1 = (xidx + 1) - xr1 * 12;
  const int xr2 = (xidx + 2) / 12, xf2 = (xidx + 2) - xr2 * 12;
  const int sx0 = offA(xr0, xf0), sx1 = offA(xr1, xf1), sx2 = offA(xr2, xf2);
  const float* xp0 = x + ((size_t)(blk * BT + xr0) * Tt) * 12 + xf0;
  const float* xp1 = x + ((size_t)(blk * BT + xr1) * Tt) * 12 + xf1;
  const float* xp2 = x + ((size_t)(blk * BT + xr2) * Tt) * 12 + xf2;
  float xn0 = 0.f, xn1 = 0.f, xn2 = 0.f;

  __syncthreads();   // zero-fill visible
  if (w == 3) {
    sm.act0[0][sx0] = (_Float16)xp0[0];
    sm.act0[0][sx1] = (_Float16)xp1[0];
    sm.act0[0][sx2] = (_Float16)xp2[0];
    xn0 = xp0[12]; xn1 = xp1[12]; xn2 = xp2[12];
  }
  __syncthreads();   // x(0) visible

  if (role <= 1) {
    // ================= PROJECTION BRANCH (w0..w3) =================
    const _Float16 (*ps)[BT * 64] = (role == 0) ? sm.act0 : sm.act1;
    floatx4 (*zd)[13 * 64]        = (role == 0) ? sm.z1 : sm.z2;
    const int lo = (role == 0) ? 1 : 3;
    const int hi = (role == 0) ? 336 : 338;
    const float* bi = (role == 0) ? bih1 : bih2;
    const float* bh = (role == 0) ? bhh1 : bhh2;

    half8   af[7][2];
    floatx4 bia[7];
#pragma unroll
    for (int i = 0; i < 7; ++i) {
      af[i][0] = (half8){}; af[i][1] = (half8){};
      bia[i] = (floatx4){0, 0, 0, 0};
      if (i < nt) {
        int m = tb + i, R = 16 * m + n, u = 4 * m + q;
        if (role == 0) {   // Wih1 over act0 layout [x(12)|h0(50)]
          af[i][0] = wfrag2(nullptr, 0, Wih1, 12, 50, R, q * 8);
          af[i][1] = wfrag2(nullptr, 0, Wih1, 12, 50, R, 32 + q * 8);
        } else {           // Wih2 over act1 layout [h1(50)]
          af[i][0] = wfrag2(Wih2, 50, nullptr, 0, 0, R, q * 8);
          af[i][1] = wfrag2(Wih2, 50, nullptr, 0, 0, R, 32 + q * 8);
        }
        if (u < 50) {
#pragma unroll
          for (int g = 0; g < 4; ++g) {
            float sc = (g == 2) ? 2.885390082f : -1.442695041f;
            bia[i][g] = sc * (bi[g * 50 + u] + bh[g * 50 + u]);
          }
        }
      }
    }

#define PBODY(NT)                                                     \
    {                                                                 \
      half8 b0 = *(const half8*)&ps[P][ro0];                          \
      half8 b1 = *(const half8*)&ps[P][ro1];                          \
      _Pragma("unroll")                                               \
      for (int i = 0; i < NT; ++i) {                                  \
        floatx4 t = bia[i];                                           \
        t = MFMA(af[i][0], b0, t);                                    \
        t = MFMA(af[i][1], b1, t);                                    \
        zd[1 - P][(tb + i) * 64 + lane] = t;                          \
      }                                                               \
    }
#define PTICK(PAR, TAU)                                               \
    {                                                                 \
      const int P = (PAR);                                            \
      if ((TAU) >= lo && (TAU) <= hi) {                               \
        if (nt == 7) PBODY(7) else PBODY(6)                           \
      }                                                               \
      if (w == 3) {                                                   \
        if ((TAU) + 1 < Tt) {                                         \
          _Float16* sw = &sm.act0[1 - P][0];                          \
          sw[sx0] = (_Float16)xn0; sw[sx1] = (_Float16)xn1;           \
          sw[sx2] = (_Float16)xn2;                                    \
        }                                                             \
        if ((TAU) + 2 < Tt) {                                         \
          xn0 = xp0[((TAU) + 2) * 12]; xn1 = xp1[((TAU) + 2) * 12];   \
          xn2 = xp2[((TAU) + 2) * 12];                                \
        }                                                             \
      }                                                               \
      __syncthreads();                                                \
    }
#pragma unroll 1
    for (int t = 0; t < 340; t += 2) {
      PTICK(0, t)
      PTICK(1, t + 1)
    }
#undef PTICK
#undef PBODY

  } else if (role == 2) {
    // ================= L0 CELL BRANCH (w4..w7) =================
    half8   af[4][2];
    floatx4 bia[4];
    float   cst[4] = {0.f, 0.f, 0.f, 0.f};
    int     wo[4];
    bool    uok[4];
#pragma unroll
    for (int i = 0; i < 4; ++i) {
      af[i][0] = (half8){}; af[i][1] = (half8){};
      bia[i] = (floatx4){0, 0, 0, 0};
      int m = (i < nt) ? (tb + i) : tb;
      int R = 16 * m + n, u = 4 * m + q;
      int uc = (u < 50) ? u : 49;
      uok[i] = (i < nt) && (u < 50);
      wo[i] = offA(n, 12 + uc);
      if (i < nt) {
        af[i][0] = wfrag2(Wih0, 12, Whh0, 12, 50, R, q * 8);
        af[i][1] = wfrag2(Wih0, 12, Whh0, 12, 50, R, 32 + q * 8);
        if (u < 50) {
#pragma unroll
          for (int g = 0; g < 4; ++g) {
            float sc = (g == 2) ? 2.885390082f : -1.442695041f;
            bia[i][g] = sc * (bih0[g * 50 + u] + bhh0[g * 50 + u]);
          }
        }
      }
    }

#define C0BODY(NT)                                                    \
    {                                                                 \
      half8 b0 = *(const half8*)&sm.act0[P][ro0];                     \
      half8 b1 = *(const half8*)&sm.act0[P][ro1];                     \
      _Float16* sw = &sm.act0[1 - P][0];                              \
      floatx4 zv[NT];                                                 \
      _Pragma("unroll")                                               \
      for (int i = 0; i < NT; ++i) zv[i] = bia[i];                    \
      _Pragma("unroll")                                               \
      for (int i = 0; i < NT; ++i) zv[i] = MFMA(af[i][0], b0, zv[i]); \
      _Pragma("unroll")                                               \
      for (int i = 0; i < NT; ++i) zv[i] = MFMA(af[i][1], b1, zv[i]); \
      _Pragma("unroll")                                               \
      for (int i = 0; i < NT; ++i) {                                  \
        float h = lstm_cell(zv[i], cst[i]);                           \
        if (uok[i]) sw[wo[i]] = (_Float16)h;                          \
      }                                                               \
    }
#define C0TICK(PAR, TAU)                                              \
    {                                                                 \
      const int P = (PAR);                                            \
      if ((TAU) <= 335) {                                             \
        if (nt == 4) C0BODY(4) else C0BODY(3)                         \
      }                                                               \
      __syncthreads();                                                \
    }
#pragma unroll 1
    for (int t = 0; t < 340; t += 2) {
      C0TICK(0, t)
      C0TICK(1, t + 1)
    }
#undef C0TICK
#undef C0BODY

  } else {
    // ================= L1/L2 CELL BRANCH (w8..w15) =================
    _Float16 (*pl)[BT * 64]       = (role == 3) ? sm.act1 : sm.act2;
    const floatx4 (*zs)[13 * 64]  = (role == 3) ? sm.z1 : sm.z2;
    const float* Whh              = (role == 3) ? Whh1 : Whh2;
    const int lo = (role == 3) ? 2 : 4;
    const int hi = (role == 3) ? 337 : 339;

    half8  af[4][2];
    float  cst[4] = {0.f, 0.f, 0.f, 0.f};
    int    wo[4];
    bool   uok[4];
#pragma unroll
    for (int i = 0; i < 4; ++i) {
      af[i][0] = (half8){}; af[i][1] = (half8){};
      int m = (i < nt) ? (tb + i) : tb;
      int R = 16 * m + n, u = 4 * m + q;
      int uc = (u < 50) ? u : 49;
      uok[i] = (i < nt) && (u < 50);
      wo[i] = offA(n, uc);
      if (i < nt) {
        af[i][0] = wfrag2(Whh, 50, nullptr, 0, 0, R, q * 8);
        af[i][1] = wfrag2(Whh, 50, nullptr, 0, 0, R, 32 + q * 8);
      }
    }

#define CZBODY(NT)                                                    \
    {                                                                 \
      half8 b0 = *(const half8*)&pl[P][ro0];                          \
      half8 b1 = *(const half8*)&pl[P][ro1];                          \
      _Float16* sw = &pl[1 - P][0];                                   \
      floatx4 zv[NT];                                                 \
      _Pragma("unroll")                                               \
      for (int i = 0; i < NT; ++i)                                    \
        zv[i] = zs[P][(tb + i) * 64 + lane];                          \
      _Pragma("unroll")                                               \
      for (int i = 0; i < NT; ++i) zv[i] = MFMA(af[i][0], b0, zv[i]); \
      _Pragma("unroll")                                               \
      for (int i = 0; i < NT; ++i) zv[i] = MFMA(af[i][1], b1, zv[i]); \
      _Pragma("unroll")                                               \
      for (int i = 0; i < NT; ++i) {                                  \
        float h = lstm_cell(zv[i], cst[i]);                           \
        if (uok[i]) sw[wo[i]] = (_Float16)h;                          \
      }                                                               \
    }
#define CZTICK(PAR, TAU)                                              \
    {                                                                 \
      const int P = (PAR);                                            \
      if ((TAU) >= lo && (TAU) <= hi) {                               \
        if (nt == 4) CZBODY(4) else CZBODY(3)                         \
      }                                                               \
      __syncthreads();                                                \
    }
#pragma unroll 1
    for (int t = 0; t < 340; t += 2) {
      CZTICK(0, t)
      CZTICK(1, t + 1)
    }
#undef CZTICK
#undef CZBODY
  }

  __syncthreads();   // all ticks done; act2[0] (h2(335)) visible

  // ---- epilogue: out[r] = b_lin + h2(335) . W_lin ----
  // L2 step 335 ran at tick 339 (P=1) -> wrote act2[0] (halfs 0..49)
  if (tid < BT) {
    float s = blin[0];
    for (int uu = 0; uu < 50; ++uu)
      s += Wlin[uu] * (float)sm.act2[0][offA(tid, uu)];
    out[blk * BT + tid] = s;
  }
}

extern "C" void kernel_launch(void* const* d_in, const int* in_sizes, int n_in,
                              void* d_out, int out_size, void* d_ws, size_t ws_size,
                              hipStream_t stream) {
  const float* x    = (const float*)d_in[0];
  const float* Wih0 = (const float*)d_in[1];
  const float* Whh0 = (const float*)d_in[2];
  const float* bih0 = (const float*)d_in[3];
  const float* bhh0 = (const float*)d_in[4];
  const float* Wih1 = (const float*)d_in[5];
  const float* Whh1 = (const float*)d_in[6];
  const float* bih1 = (const float*)d_in[7];
  const float* bhh1 = (const float*)d_in[8];
  const float* Wih2 = (const float*)d_in[9];
  const float* Whh2 = (const float*)d_in[10];
  const float* bih2 = (const float*)d_in[11];
  const float* bhh2 = (const float*)d_in[12];
  const float* Wlin = (const float*)d_in[13];
  const float* blin = (const float*)d_in[14];
  float* outp = (float*)d_out;

  dim3 grid(Bsz / BT);   // 256 blocks, 1 per CU
  dim3 block(NTH);       // 16 waves: each SIMD = 1 proj + 3 cell
  lstm_mfma_kernel<<<grid, block, 0, stream>>>(
      x, Wih0, Whh0, bih0, bhh0, Wih1, Whh1, bih1, bhh1,
      Wih2, Whh2, bih2, bhh2, Wlin, blin, outp);
}